// Round 5
// baseline (576.920 us; speedup 1.0000x reference)
//
#include <hip/hip_runtime.h>
#include <stdint.h>

#define NB 1024
#define N1P 116
#define N2P 200
#define HD 32
#define T1 464   // NB*N1P/256  (118784 rows, exact)
#define T2 800   // NB*N2P/256  (204800 rows, exact)

// ---------------------------------------------------------------------------
// R10 (counter-driven):
//  * graph_fused: edge lists (cols/vals) loaded ONCE into registers per node
//    (8x16B, issued before S-staging so HBM latency hides under it); agg1 and
//    agg2 both per-node, reusing the same edge registers -> agg2 has zero
//    global loads, and ~41 MB of HBM refetch disappears.
//  * gemm1: LDS slices are wave-private (wave w writes/reads slices 4w..4w+3)
//    -> __syncthreads() per chunk was pure overhead (drains vmcnt(0), kills
//    the prefetch). Replaced with per-wave counted s_waitcnt vmcnt(4): next
//    chunk's 4 loads stay in flight across the wait (T4 pattern). Tail-chunk
//    loads clamp the source (dup data, never read) instead of predicating,
//    keeping exactly 4 VMEM ops per issue so the count is exact.
//  * launch_bounds(256,3) everywhere: VGPR cap 168, no allocator squeeze
//    (R7/R8 lesson: caps below natural usage -> scratch spill catastrophe).
// ---------------------------------------------------------------------------

__device__ __forceinline__ void gll16(const void* g, void* l) {
    __builtin_amdgcn_global_load_lds(
        (const __attribute__((address_space(1))) void*)g,
        (__attribute__((address_space(3))) void*)l, 16, 0, 0);
}

// ---------------------------------------------------------------------------
// K1: dense GEMM  S[row, :] = X[row, :] @ W   (K x 32), 256 rows per block.
// Barrier-free: per-wave private LDS slices + counted vmcnt.
// ---------------------------------------------------------------------------
template <int K>
__device__ void gemm1_tile(const float* __restrict__ xg,
                           const float* __restrict__ W,
                           float* __restrict__ Sout, float* sX) {
    constexpr int KC = 16;                 // k-chunk (floats)
    constexpr int NC = (K + KC - 1) / KC;  // 8 for 116, 13 for 200
    const int tid = threadIdx.x;
    const int lane = tid & 63;
    const int wave = tid >> 6;
    const int ris = lane >> 2;             // row within 16-row slice
    const int pq = lane & 3;               // float4 slot this lane fills

    float acc[32];
#pragma unroll
    for (int c = 0; c < 32; ++c) acc[c] = 0.f;

    // One chunk = 4 gll16 per wave (one per 16-row slice). Lane l of slice s
    // writes LDS bytes [s*1024 + l*16). Swizzle: slot p holds logical col
    // group p^((row>>1)&3). Tail chunks: clamp source (dup data, never read)
    // so EXACTLY 4 VMEM ops issue per call -> vmcnt counting stays exact.
    auto issue = [&](int kc, int buf) {
        const int k0 = kc * KC;
        const int pieces = ((K - k0) < KC ? (K - k0) : KC) >> 2;
#pragma unroll
        for (int i = 0; i < 4; ++i) {
            const int s = wave * 4 + i;
            const int row = s * 16 + ris;
            int gg = pq ^ ((row >> 1) & 3);
            if (gg >= pieces) gg = 0;      // clamped dup; slot never read
            gll16(xg + (size_t)row * K + k0 + gg * 4,
                  sX + buf * 4096 + s * 256);
        }
    };

    issue(0, 0);

    const int sw = (tid >> 1) & 3;         // my row's swizzle key
    int buf = 0;
#pragma unroll 1
    for (int kc = 0; kc < NC; ++kc) {
        if (kc + 1 < NC) {
            issue(kc + 1, buf ^ 1);        // 8 in flight (4 old + 4 new)
            asm volatile("s_waitcnt vmcnt(4)" ::: "memory");  // old 4 done
        } else {
            asm volatile("s_waitcnt vmcnt(0)" ::: "memory");  // drain last
        }
        __builtin_amdgcn_sched_barrier(0);
        const int k0 = kc * KC;
        const int kw = (K - k0) < KC ? (K - k0) : KC;
        const float* xrow = sX + buf * 4096 + tid * 16;
#pragma unroll
        for (int G = 0; G < 4; ++G) {
            if (G * 4 < kw) {
                const float4 x4 = *(const float4*)&xrow[(G ^ sw) * 4];
                const float* wb = W + (size_t)(k0 + G * 4) * 32;
#pragma unroll
                for (int kk = 0; kk < 4; ++kk) {
                    const float xs = (&x4.x)[kk];
                    const float* w = wb + kk * 32;     // uniform -> s_load
#pragma unroll
                    for (int c4 = 0; c4 < 8; ++c4) {
                        const float4 wv = *(const float4*)&w[c4 * 4];
                        acc[c4 * 4 + 0] += xs * wv.x;
                        acc[c4 * 4 + 1] += xs * wv.y;
                        acc[c4 * 4 + 2] += xs * wv.z;
                        acc[c4 * 4 + 3] += xs * wv.w;
                    }
                }
            }
        }
        buf ^= 1;
    }

    float* srow = Sout + (size_t)tid * 32;
#pragma unroll
    for (int c4 = 0; c4 < 8; ++c4) {
        float4 o;
        o.x = acc[c4 * 4 + 0]; o.y = acc[c4 * 4 + 1];
        o.z = acc[c4 * 4 + 2]; o.w = acc[c4 * 4 + 3];
        *(float4*)&srow[c4 * 4] = o;
    }
}

__global__ __launch_bounds__(256, 3) void gemm1_kernel(
        const float* __restrict__ x1, const float* __restrict__ W1a,
        float* __restrict__ S1,
        const float* __restrict__ x2, const float* __restrict__ W2a,
        float* __restrict__ S2) {
    __shared__ float sX[2 * 4096];         // 32 KB
    const int bid = blockIdx.x;
    if (bid < T1) {
        gemm1_tile<N1P>(x1 + (size_t)bid * 256 * N1P, W1a,
                        S1 + (size_t)bid * 256 * 32, sX);
    } else {
        const int t = bid - T1;
        gemm1_tile<N2P>(x2 + (size_t)t * 256 * N2P, W2a,
                        S2 + (size_t)t * 256 * 32, sX);
    }
}

// ---------------------------------------------------------------------------
// K2: per-graph. Edges in registers (loaded once), both aggs per-node.
// stage S -> [agg1+relu+GEMM2] -> write s2 -> [agg2+relu from regs]
// -> write h2 -> pool.
// ---------------------------------------------------------------------------
template <int NP>
__device__ void graph_phase(int g, const float* __restrict__ S,
                            const int* __restrict__ cols,
                            const float* __restrict__ vals,
                            const float* __restrict__ ba,
                            const float* __restrict__ Wb,
                            const float* __restrict__ bb,
                            float* __restrict__ feats, int foff,
                            float* sSup) {
    constexpr int ST = 33;                 // conflict-free row stride
    const int tid = threadIdx.x;
    const int h = tid & 31, sl = tid >> 5;
    const int base = g * NP;

    // ---- 0. edge loads FIRST: latency hides under S staging ----
    int4 ec0, ec1, ec2, ec3;
    float4 ev0, ev1, ev2, ev3;
    if (tid < NP) {
        const int4* c4p = (const int4*)(cols + ((size_t)(base + tid)) * 16);
        const float4* v4p = (const float4*)(vals + ((size_t)(base + tid)) * 16);
        ec0 = c4p[0]; ec1 = c4p[1]; ec2 = c4p[2]; ec3 = c4p[3];
        ev0 = v4p[0]; ev1 = v4p[1]; ev2 = v4p[2]; ev3 = v4p[3];
    }

    // ---- 1. stage S block (NP x 32, contiguous) into sSup (stride 33) ----
    const float* Sg = S + (size_t)base * 32;
    constexpr int PIECES = NP * 8;
    constexpr int PSL = (PIECES + 255) / 256;
#pragma unroll
    for (int q = 0; q < PSL; ++q) {
        const int i = tid + q * 256;
        if (i < PIECES) {
            const float4 v = *(const float4*)(Sg + (size_t)i * 4);
            *(float4*)&sSup[(i >> 3) * ST + (i & 7) * 4] = v;
        }
    }
    __syncthreads();

    // 4 neighbor-rows x 32 features accumulate (static indices only)
    auto agg_step = [&](const int4& c, const float4& v, float* hx) {
        const float* r0 = &sSup[(c.x - base) * ST];
        const float* r1 = &sSup[(c.y - base) * ST];
        const float* r2 = &sSup[(c.z - base) * ST];
        const float* r3 = &sSup[(c.w - base) * ST];
#pragma unroll
        for (int c8 = 0; c8 < 8; ++c8) {
            const float4 s0 = *(const float4*)&r0[c8 * 4];
            const float4 s1 = *(const float4*)&r1[c8 * 4];
            const float4 s2 = *(const float4*)&r2[c8 * 4];
            const float4 s3 = *(const float4*)&r3[c8 * 4];
            hx[c8 * 4 + 0] += v.x * s0.x + v.y * s1.x + v.z * s2.x + v.w * s3.x;
            hx[c8 * 4 + 1] += v.x * s0.y + v.y * s1.y + v.z * s2.y + v.w * s3.y;
            hx[c8 * 4 + 2] += v.x * s0.z + v.y * s1.z + v.z * s2.z + v.w * s3.z;
            hx[c8 * 4 + 3] += v.x * s0.w + v.y * s1.w + v.z * s2.w + v.w * s3.w;
        }
    };

    // ---- 2. fused agg1 + relu + GEMM2, one node per thread ----
    float acc2[32];
    if (tid < NP) {
        float h1[32];
#pragma unroll
        for (int k = 0; k < 32; ++k) h1[k] = ba[k];       // uniform s_loads
        agg_step(ec0, ev0, h1);
        agg_step(ec1, ev1, h1);
        agg_step(ec2, ev2, h1);
        agg_step(ec3, ev3, h1);
#pragma unroll
        for (int k = 0; k < 32; ++k) h1[k] = fmaxf(h1[k], 0.f);

#pragma unroll
        for (int c = 0; c < 32; ++c) acc2[c] = 0.f;
#pragma unroll
        for (int k = 0; k < 32; ++k) {
            const float xs = h1[k];
            const float* w = Wb + k * 32;                 // uniform -> s_load
#pragma unroll
            for (int c4 = 0; c4 < 8; ++c4) {
                const float4 wv = *(const float4*)&w[c4 * 4];
                acc2[c4 * 4 + 0] += xs * wv.x;
                acc2[c4 * 4 + 1] += xs * wv.y;
                acc2[c4 * 4 + 2] += xs * wv.z;
                acc2[c4 * 4 + 3] += xs * wv.w;
            }
        }
    }
    __syncthreads();                       // all agg1 reads of sSup done

    if (tid < NP) {
#pragma unroll
        for (int c4 = 0; c4 < 8; ++c4) {
            float4 o;
            o.x = acc2[c4 * 4 + 0]; o.y = acc2[c4 * 4 + 1];
            o.z = acc2[c4 * 4 + 2]; o.w = acc2[c4 * 4 + 3];
            *(float4*)&sSup[tid * ST + c4 * 4] = o;
        }
    }
    __syncthreads();

    // ---- 3. agg2 + relu per node, edges from REGISTERS (no global) ----
    float h2[32];
    if (tid < NP) {
#pragma unroll
        for (int k = 0; k < 32; ++k) h2[k] = bb[k];       // uniform s_loads
        agg_step(ec0, ev0, h2);
        agg_step(ec1, ev1, h2);
        agg_step(ec2, ev2, h2);
        agg_step(ec3, ev3, h2);
#pragma unroll
        for (int k = 0; k < 32; ++k) h2[k] = fmaxf(h2[k], 0.f);
    }
    __syncthreads();                       // all agg2 reads of sSup done

    if (tid < NP) {
#pragma unroll
        for (int c4 = 0; c4 < 8; ++c4) {
            float4 o;
            o.x = h2[c4 * 4 + 0]; o.y = h2[c4 * 4 + 1];
            o.z = h2[c4 * 4 + 2]; o.w = h2[c4 * 4 + 3];
            *(float4*)&sSup[tid * ST + c4 * 4] = o;
        }
    }
    __syncthreads();

    // ---- 4. pool mean+max over nodes ----
    float sum = 0.f, mx = -1e30f;
#pragma unroll 1
    for (int n = sl; n < NP; n += 8) {
        const float v = sSup[n * ST + h];
        sum += v;
        mx = fmaxf(mx, v);
    }
    __syncthreads();                       // pool reads done; sSup reusable

    sSup[tid] = sum;
    sSup[256 + tid] = mx;
    __syncthreads();
    if (tid < 32) {
#pragma unroll
        for (int q = 1; q < 8; ++q) {
            sum += sSup[tid + 32 * q];
            mx = fmaxf(mx, sSup[256 + tid + 32 * q]);
        }
        feats[(size_t)g * 128 + foff + tid] = sum * (1.0f / NP);
        feats[(size_t)g * 128 + foff + 32 + tid] = mx;
    }
}

__global__ __launch_bounds__(256, 3) void graph_fused(
        const float* __restrict__ S1, const int* __restrict__ cols1,
        const float* __restrict__ vals1, const float* __restrict__ b1a,
        const float* __restrict__ W1b, const float* __restrict__ b1b,
        const float* __restrict__ S2, const int* __restrict__ cols2,
        const float* __restrict__ vals2, const float* __restrict__ b2a,
        const float* __restrict__ W2b, const float* __restrict__ b2b,
        float* __restrict__ feats) {
    __shared__ float sSup[N2P * 33];       // 26.4 KB
    const int bid = blockIdx.x;
    const int g = bid >> 1;                // interleave branches: tail balance
    if ((bid & 1) == 0)
        graph_phase<N1P>(g, S1, cols1, vals1, b1a, W1b, b1b, feats, 0, sSup);
    else
        graph_phase<N2P>(g, S2, cols2, vals2, b2a, W2b, b2b, feats, 64, sSup);
}

// ---------------------------------------------------------------------------
// Fallback: proven R5 monolithic per-graph kernel (used if ws too small)
// ---------------------------------------------------------------------------
template <int ST>
__device__ __forceinline__ void agg_phase_fb(int base, int NPv,
                                             const int* __restrict__ cols,
                                             const float* __restrict__ vals,
                                             const float* __restrict__ sup,
                                             float bias, float* __restrict__ outh,
                                             int tid) {
    const int h = tid & 31;
    for (int n = tid >> 5; n < NPv; n += 8) {
        const int4* c4 = (const int4*)(cols + ((size_t)base + n) * 16);
        const float4* v4 = (const float4*)(vals + ((size_t)base + n) * 16);
        float a = bias;
#pragma unroll
        for (int q = 0; q < 4; ++q) {
            const int4 c = c4[q];
            const float4 v = v4[q];
            a += v.x * sup[(c.x - base) * ST + h];
            a += v.y * sup[(c.y - base) * ST + h];
            a += v.z * sup[(c.z - base) * ST + h];
            a += v.w * sup[(c.w - base) * ST + h];
        }
        outh[n * ST + h] = fmaxf(a, 0.f);
    }
}

template <int NP>
__device__ void branch_graph(int g,
                             const float* __restrict__ X,
                             const int* __restrict__ cols,
                             const float* __restrict__ vals,
                             const float* __restrict__ Wa,
                             const float* __restrict__ ba,
                             const float* __restrict__ Wb,
                             const float* __restrict__ bb,
                             float* __restrict__ feats, int foff,
                             float* sSup, float* sH) {
    constexpr int ST = 33;
    constexpr int KC = 16;
    constexpr int SXS = 20;
    constexpr int NSLOT = NP * 4;
    constexpr int PSL = (NSLOT + 255) / 256;

    const int tid = threadIdx.x;
    const int base = g * NP;
    const float* xg = X + (size_t)base * NP;
    const float bA = ba[tid & 31];
    const float bB = bb[tid & 31];

    float* sX = sSup;

    float acc[32];
#pragma unroll
    for (int c = 0; c < 32; ++c) acc[c] = 0.f;

    const int NC = (NP + KC - 1) / KC;

    float4 cur[PSL], nxt[PSL];

    auto load_chunk = [&](int kc, float4* buf) {
        const int k0 = kc * KC;
        const int kw = (NP - k0) < KC ? (NP - k0) : KC;
        const int pieces = kw >> 2;
#pragma unroll
        for (int q = 0; q < PSL; ++q) {
            const int i = tid + q * 256;
            float4 v = make_float4(0.f, 0.f, 0.f, 0.f);
            if (i < NSLOT) {
                const int row = i >> 2, p = i & 3;
                if (p < pieces)
                    v = *(const float4*)(xg + (size_t)row * NP + k0 + p * 4);
            }
            buf[q] = v;
        }
    };
    auto store_chunk = [&](const float4* buf) {
#pragma unroll
        for (int q = 0; q < PSL; ++q) {
            const int i = tid + q * 256;
            if (i < NSLOT) {
                const int row = i >> 2, p = i & 3;
                *(float4*)&sX[row * SXS + p * 4] = buf[q];
            }
        }
    };

    load_chunk(0, cur);
#pragma unroll 1
    for (int kc = 0; kc < NC; ++kc) {
        __syncthreads();
        store_chunk(cur);
        __syncthreads();
        if (kc + 1 < NC) load_chunk(kc + 1, nxt);
        const int k0 = kc * KC;
        const int kw = (NP - k0) < KC ? (NP - k0) : KC;
        if (tid < NP) {
            const float* xrow = &sX[tid * SXS];
            const float* wb0 = Wa + (size_t)k0 * 32;
#pragma unroll 1
            for (int k4 = 0; k4 < kw; k4 += 4) {
                const float4 x4 = *(const float4*)&xrow[k4];
#pragma unroll
                for (int kk = 0; kk < 4; ++kk) {
                    const float xs = (&x4.x)[kk];
                    const float* w = wb0 + (k4 + kk) * 32;
#pragma unroll
                    for (int c4 = 0; c4 < 8; ++c4) {
                        const float4 wv = *(const float4*)&w[c4 * 4];
                        acc[c4 * 4 + 0] += xs * wv.x;
                        acc[c4 * 4 + 1] += xs * wv.y;
                        acc[c4 * 4 + 2] += xs * wv.z;
                        acc[c4 * 4 + 3] += xs * wv.w;
                    }
                }
            }
        }
#pragma unroll
        for (int q = 0; q < PSL; ++q) cur[q] = nxt[q];
    }
    __syncthreads();

    if (tid < NP) {
#pragma unroll
        for (int c4 = 0; c4 < 8; ++c4) {
            float4 o;
            o.x = acc[c4 * 4 + 0]; o.y = acc[c4 * 4 + 1];
            o.z = acc[c4 * 4 + 2]; o.w = acc[c4 * 4 + 3];
            *(float4*)&sSup[tid * ST + c4 * 4] = o;
        }
    }
    __syncthreads();

    agg_phase_fb<ST>(base, NP, cols, vals, sSup, bA, sH, tid);
    __syncthreads();

    if (tid < NP) {
        float acc2[32];
#pragma unroll
        for (int c = 0; c < 32; ++c) acc2[c] = 0.f;
        const float* xrow = &sH[tid * ST];
#pragma unroll 1
        for (int k4 = 0; k4 < 32; k4 += 4) {
            const float4 x4 = *(const float4*)&xrow[k4];
#pragma unroll
            for (int kk = 0; kk < 4; ++kk) {
                const float xs = (&x4.x)[kk];
                const float* w = Wb + (k4 + kk) * 32;
#pragma unroll
                for (int c4 = 0; c4 < 8; ++c4) {
                    const float4 wv = *(const float4*)&w[c4 * 4];
                    acc2[c4 * 4 + 0] += xs * wv.x;
                    acc2[c4 * 4 + 1] += xs * wv.y;
                    acc2[c4 * 4 + 2] += xs * wv.z;
                    acc2[c4 * 4 + 3] += xs * wv.w;
                }
            }
        }
#pragma unroll
        for (int c4 = 0; c4 < 8; ++c4) {
            float4 o;
            o.x = acc2[c4 * 4 + 0]; o.y = acc2[c4 * 4 + 1];
            o.z = acc2[c4 * 4 + 2]; o.w = acc2[c4 * 4 + 3];
            *(float4*)&sSup[tid * ST + c4 * 4] = o;
        }
    }
    __syncthreads();

    agg_phase_fb<ST>(base, NP, cols, vals, sSup, bB, sH, tid);
    __syncthreads();

    const int h = tid & 31, sl = tid >> 5;
    float sum = 0.f, mx = -1e30f;
    for (int n = sl; n < NP; n += 8) {
        const float v = sH[n * ST + h];
        sum += v;
        mx = fmaxf(mx, v);
    }
    float* sS = sSup;
    float* sM = sSup + 256;
    sS[tid] = sum;
    sM[tid] = mx;
    __syncthreads();
    if (tid < 32) {
#pragma unroll
        for (int q = 1; q < 8; ++q) {
            sum += sS[tid + 32 * q];
            mx = fmaxf(mx, sM[tid + 32 * q]);
        }
        feats[(size_t)g * 128 + foff + tid] = sum * (1.0f / NP);
        feats[(size_t)g * 128 + foff + 32 + tid] = mx;
    }
}

__global__ __launch_bounds__(256, 3) void fused_branches(
        const float* __restrict__ x1, const int* __restrict__ cols1,
        const float* __restrict__ vals1,
        const float* __restrict__ W1a, const float* __restrict__ b1a,
        const float* __restrict__ W1b, const float* __restrict__ b1b,
        const float* __restrict__ x2, const int* __restrict__ cols2,
        const float* __restrict__ vals2,
        const float* __restrict__ W2a, const float* __restrict__ b2a,
        const float* __restrict__ W2b, const float* __restrict__ b2b,
        float* __restrict__ feats) {
    __shared__ float sSup[N2P * 33];
    __shared__ float sH[N2P * 33];
    const int bid = blockIdx.x;
    if (bid < NB) {
        branch_graph<N1P>(bid, x1, cols1, vals1, W1a, b1a, W1b, b1b, feats, 0,
                          sSup, sH);
    } else {
        branch_graph<N2P>(bid - NB, x2, cols2, vals2, W2a, b2a, W2b, b2b, feats,
                          64, sSup, sH);
    }
}

// ---------------------------------------------------------------------------
// MLP head: [B,128] -> relu(fc1) -> relu(fc2) -> fc3 -> [B,2]
// ---------------------------------------------------------------------------
__global__ __launch_bounds__(256) void mlp_head(const float* __restrict__ feats,
                                                const float* __restrict__ W1,
                                                const float* __restrict__ b1,
                                                const float* __restrict__ W2,
                                                const float* __restrict__ b2,
                                                const float* __restrict__ W3,
                                                const float* __restrict__ b3,
                                                float* __restrict__ out) {
    __shared__ float sW1[128 * 32];
    __shared__ float sW2[32 * 16];
    __shared__ float sW3[16 * 2];
    __shared__ float sB1[32], sB2[16], sB3[2];
    __shared__ float sF[8 * 128];
    __shared__ float sH1[8 * 32];
    __shared__ float sH2[8 * 16];

    const int tid = threadIdx.x;
    for (int idx = tid; idx < 128 * 32; idx += 256) sW1[idx] = W1[idx];
    for (int idx = tid; idx < 32 * 16; idx += 256) sW2[idx] = W2[idx];
    if (tid < 32) { sW3[tid] = W3[tid]; sB1[tid] = b1[tid]; }
    if (tid < 16) sB2[tid] = b2[tid];
    if (tid < 2) sB3[tid] = b3[tid];
    const long g0 = (long)blockIdx.x * 8;
    for (int idx = tid; idx < 1024; idx += 256) sF[idx] = feats[g0 * 128 + idx];
    __syncthreads();

    const int g = tid >> 5, h = tid & 31;
    float a1 = sB1[h];
#pragma unroll 4
    for (int k = 0; k < 128; ++k) a1 += sF[g * 128 + k] * sW1[k * 32 + h];
    sH1[g * 32 + h] = fmaxf(a1, 0.f);
    __syncthreads();

    if (h < 16) {
        float a2 = sB2[h];
#pragma unroll
        for (int k = 0; k < 32; ++k) a2 += sH1[g * 32 + k] * sW2[k * 16 + h];
        sH2[g * 16 + h] = fmaxf(a2, 0.f);
    }
    __syncthreads();

    if (h < 2) {
        float a3 = sB3[h];
#pragma unroll
        for (int k = 0; k < 16; ++k) a3 += sH2[g * 16 + k] * sW3[k * 2 + h];
        out[(g0 + g) * 2 + h] = a3;
    }
}

// ---------------------------------------------------------------------------
extern "C" void kernel_launch(void* const* d_in, const int* in_sizes, int n_in,
                              void* d_out, int out_size, void* d_ws, size_t ws_size,
                              hipStream_t stream) {
    const int*   cols1 = (const int*)d_in[1];
    const float* vals1 = (const float*)d_in[2];
    const float* x1    = (const float*)d_in[3];
    const int*   cols2 = (const int*)d_in[5];
    const float* vals2 = (const float*)d_in[6];
    const float* x2    = (const float*)d_in[7];
    const float* W1a = (const float*)d_in[8];
    const float* b1a = (const float*)d_in[9];
    const float* W1b = (const float*)d_in[10];
    const float* b1b = (const float*)d_in[11];
    const float* W2a = (const float*)d_in[12];
    const float* b2a = (const float*)d_in[13];
    const float* W2b = (const float*)d_in[14];
    const float* b2b = (const float*)d_in[15];
    const float* fc1_W = (const float*)d_in[16];
    const float* fc1_b = (const float*)d_in[17];
    const float* fc2_W = (const float*)d_in[18];
    const float* fc2_b = (const float*)d_in[19];
    const float* fc3_W = (const float*)d_in[20];
    const float* fc3_b = (const float*)d_in[21];
    float* out = (float*)d_out;

    float* feats = (float*)d_ws;                       // NB*128 floats
    const size_t FEATS_N = (size_t)NB * 128;
    const size_t S1_N = (size_t)NB * N1P * 32;         // 3.80M floats
    const size_t S2_N = (size_t)NB * N2P * 32;         // 6.55M floats
    const size_t need = (FEATS_N + S1_N + S2_N) * sizeof(float);  // ~42 MB

    if (ws_size >= need) {
        float* S1 = feats + FEATS_N;
        float* S2 = S1 + S1_N;
        gemm1_kernel<<<T1 + T2, 256, 0, stream>>>(x1, W1a, S1, x2, W2a, S2);
        graph_fused<<<2 * NB, 256, 0, stream>>>(
            S1, cols1, vals1, b1a, W1b, b1b,
            S2, cols2, vals2, b2a, W2b, b2b, feats);
    } else {
        fused_branches<<<2 * NB, 256, 0, stream>>>(
            x1, cols1, vals1, W1a, b1a, W1b, b1b,
            x2, cols2, vals2, W2a, b2a, W2b, b2b, feats);
    }

    mlp_head<<<NB / 8, 256, 0, stream>>>(feats, fc1_W, fc1_b, fc2_W, fc2_b,
                                         fc3_W, fc3_b, out);
}

// Round 6
// 530.448 us; speedup vs baseline: 1.0876x; 1.0876x over previous
//
#include <hip/hip_runtime.h>
#include <stdint.h>

#define NB 1024
#define N1P 116
#define N2P 200
#define HD 32
#define T1 464   // NB*N1P/256  (118784 rows, exact)
#define T2 800   // NB*N2P/256  (204800 rows, exact)

// ---------------------------------------------------------------------------
// R11 (counter-driven):
//  * gemm1 rewritten LDS-FREE. Thread t computes row t and reads ONLY row t
//    of X -> there was never any cross-thread X reuse; LDS staging (and all
//    its barrier/vmcnt serialization) was a detour. Now: per 16-float chunk,
//    4x dwordx4 direct to registers (one fully-consumed 64B line per lane),
//    double-buffered with STATIC cur/nxt alternation (no dynamic indexing,
//    no copies), W via wave-uniform s_loads. Zero barriers, zero LDS.
//  * graph_fused reverted VERBATIM to the R9 structure (proven 154 us):
//    per-node fused agg1+GEMM2, strided all-thread agg2 straight into pool
//    registers. R10's edges-in-registers variant (216 us) showed memory
//    traffic was never the limiter; phase parallelism is.
// ---------------------------------------------------------------------------

// ---------------------------------------------------------------------------
// K1: dense GEMM  S[row, :] = X[row, :] @ W  (K x 32). One thread = one row.
// ---------------------------------------------------------------------------
template <int K>
__device__ void gemm1_row(const float* __restrict__ xr,
                          const float* __restrict__ W,
                          float* __restrict__ srow) {
    constexpr int KC = 16;
    constexpr int NC = (K + KC - 1) / KC;  // 8 for 116, 13 for 200

    float acc[32];
#pragma unroll
    for (int c = 0; c < 32; ++c) acc[c] = 0.f;

    float4 cA[4], cB[4];

    auto ld = [&](int kc, float4* b) {
        const int k0 = kc * KC;
        const int pieces = ((K - k0) < KC ? (K - k0) : KC) >> 2;
#pragma unroll
        for (int p = 0; p < 4; ++p)
            b[p] = (p < pieces) ? *(const float4*)(xr + k0 + p * 4)
                                : make_float4(0.f, 0.f, 0.f, 0.f);
    };
    auto comp = [&](int kc, const float4* b) {
        const int k0 = kc * KC;
        const int kw = (K - k0) < KC ? (K - k0) : KC;
#pragma unroll
        for (int G = 0; G < 4; ++G) {
            if (G * 4 < kw) {
                const float4 x4 = b[G];
                const float* wb = W + (size_t)(k0 + G * 4) * 32;
#pragma unroll
                for (int kk = 0; kk < 4; ++kk) {
                    const float xs = (&x4.x)[kk];
                    const float* w = wb + kk * 32;     // uniform -> s_load
#pragma unroll
                    for (int c4 = 0; c4 < 8; ++c4) {
                        const float4 wv = *(const float4*)&w[c4 * 4];
                        acc[c4 * 4 + 0] += xs * wv.x;
                        acc[c4 * 4 + 1] += xs * wv.y;
                        acc[c4 * 4 + 2] += xs * wv.z;
                        acc[c4 * 4 + 3] += xs * wv.w;
                    }
                }
            }
        }
    };

    ld(0, cA);
#pragma unroll 1
    for (int kc = 0; kc < NC; kc += 2) {
        if (kc + 1 < NC) ld(kc + 1, cB);   // prefetch B while A computes
        comp(kc, cA);
        if (kc + 2 < NC) ld(kc + 2, cA);   // prefetch A while B computes
        if (kc + 1 < NC) comp(kc + 1, cB);
    }

#pragma unroll
    for (int c4 = 0; c4 < 8; ++c4) {
        float4 o;
        o.x = acc[c4 * 4 + 0]; o.y = acc[c4 * 4 + 1];
        o.z = acc[c4 * 4 + 2]; o.w = acc[c4 * 4 + 3];
        *(float4*)&srow[c4 * 4] = o;
    }
}

__global__ __launch_bounds__(256, 3) void gemm1_kernel(
        const float* __restrict__ x1, const float* __restrict__ W1a,
        float* __restrict__ S1,
        const float* __restrict__ x2, const float* __restrict__ W2a,
        float* __restrict__ S2) {
    const int bid = blockIdx.x;
    const int tid = threadIdx.x;
    if (bid < T1) {
        const size_t row = (size_t)bid * 256 + tid;
        gemm1_row<N1P>(x1 + row * N1P, W1a, S1 + row * 32);
    } else {
        const size_t row = (size_t)(bid - T1) * 256 + tid;
        gemm1_row<N2P>(x2 + row * N2P, W2a, S2 + row * 32);
    }
}

// ---------------------------------------------------------------------------
// K2: per-graph (R9 structure, verbatim — proven 154 us).
// stage S -> [agg1+GEMM2 fused in registers] -> agg2+pool (strided, all thr)
// ---------------------------------------------------------------------------
template <int NP>
__device__ void graph_phase(int g, const float* __restrict__ S,
                            const int* __restrict__ cols,
                            const float* __restrict__ vals,
                            const float* __restrict__ ba,
                            const float* __restrict__ Wb,
                            const float* __restrict__ bb,
                            float* __restrict__ feats, int foff,
                            float* sSup) {
    constexpr int ST = 33;                 // proven conflict-free row stride
    const int tid = threadIdx.x;
    const int h = tid & 31, sl = tid >> 5;
    const int base = g * NP;

    // ---- stage S block (NP x 32, contiguous) into sSup (stride 33) ----
    const float* Sg = S + (size_t)base * 32;
    constexpr int PIECES = NP * 8;
    constexpr int PSL = (PIECES + 255) / 256;
#pragma unroll
    for (int q = 0; q < PSL; ++q) {
        const int i = tid + q * 256;
        if (i < PIECES) {
            const float4 v = *(const float4*)(Sg + (size_t)i * 4);
            *(float4*)&sSup[(i >> 3) * ST + (i & 7) * 4] = v;
        }
    }
    __syncthreads();

    // ---- fused agg1 + relu + GEMM2, one node per thread, all registers ----
    float acc2[32];
    if (tid < NP) {
        float h1[32];
#pragma unroll
        for (int k = 0; k < 32; ++k) h1[k] = ba[k];       // uniform s_loads
        const int4* c4p = (const int4*)(cols + ((size_t)(base + tid)) * 16);
        const float4* v4p = (const float4*)(vals + ((size_t)(base + tid)) * 16);
#pragma unroll
        for (int q = 0; q < 4; ++q) {
            const int4 c = c4p[q];
            const float4 v = v4p[q];
            const float* r0 = &sSup[(c.x - base) * ST];
            const float* r1 = &sSup[(c.y - base) * ST];
            const float* r2 = &sSup[(c.z - base) * ST];
            const float* r3 = &sSup[(c.w - base) * ST];
#pragma unroll
            for (int c8 = 0; c8 < 8; ++c8) {
                const float4 s0 = *(const float4*)&r0[c8 * 4];
                const float4 s1 = *(const float4*)&r1[c8 * 4];
                const float4 s2 = *(const float4*)&r2[c8 * 4];
                const float4 s3 = *(const float4*)&r3[c8 * 4];
                h1[c8 * 4 + 0] += v.x * s0.x + v.y * s1.x + v.z * s2.x + v.w * s3.x;
                h1[c8 * 4 + 1] += v.x * s0.y + v.y * s1.y + v.z * s2.y + v.w * s3.y;
                h1[c8 * 4 + 2] += v.x * s0.z + v.y * s1.z + v.z * s2.z + v.w * s3.z;
                h1[c8 * 4 + 3] += v.x * s0.w + v.y * s1.w + v.z * s2.w + v.w * s3.w;
            }
        }
#pragma unroll
        for (int k = 0; k < 32; ++k) h1[k] = fmaxf(h1[k], 0.f);

        // support2[tid,:] = h1 @ Wb  (Wb uniform -> s_loads)
#pragma unroll
        for (int c = 0; c < 32; ++c) acc2[c] = 0.f;
#pragma unroll
        for (int k = 0; k < 32; ++k) {
            const float xs = h1[k];
            const float* w = Wb + k * 32;
#pragma unroll
            for (int c4 = 0; c4 < 8; ++c4) {
                const float4 wv = *(const float4*)&w[c4 * 4];
                acc2[c4 * 4 + 0] += xs * wv.x;
                acc2[c4 * 4 + 1] += xs * wv.y;
                acc2[c4 * 4 + 2] += xs * wv.z;
                acc2[c4 * 4 + 3] += xs * wv.w;
            }
        }
    }
    __syncthreads();                       // all agg1 reads of sSup done

    if (tid < NP) {
#pragma unroll
        for (int c4 = 0; c4 < 8; ++c4) {
            float4 o;
            o.x = acc2[c4 * 4 + 0]; o.y = acc2[c4 * 4 + 1];
            o.z = acc2[c4 * 4 + 2]; o.w = acc2[c4 * 4 + 3];
            *(float4*)&sSup[tid * ST + c4 * 4] = o;
        }
    }
    __syncthreads();

    // ---- agg2 + relu + pool: runtime loop (no unroll -> no hoist) ----
    const float bB = bb[h];
    float sum = 0.f, mx = -1e30f;
#pragma unroll 1
    for (int n = sl; n < NP; n += 8) {
        const int4* c4 = (const int4*)(cols + ((size_t)(base + n)) * 16);
        const float4* v4 = (const float4*)(vals + ((size_t)(base + n)) * 16);
        float a0 = 0.f, a1 = 0.f, a2 = 0.f, a3 = 0.f;
#pragma unroll
        for (int q = 0; q < 4; ++q) {
            const int4 c = c4[q];
            const float4 v = v4[q];
            a0 += v.x * sSup[(c.x - base) * ST + h];
            a1 += v.y * sSup[(c.y - base) * ST + h];
            a2 += v.z * sSup[(c.z - base) * ST + h];
            a3 += v.w * sSup[(c.w - base) * ST + h];
        }
        const float v2 = fmaxf(bB + ((a0 + a1) + (a2 + a3)), 0.f);
        sum += v2;
        mx = fmaxf(mx, v2);
    }
    __syncthreads();                       // agg2 reads done; sSup reusable

    sSup[tid] = sum;
    sSup[256 + tid] = mx;
    __syncthreads();
    if (tid < 32) {
#pragma unroll
        for (int q = 1; q < 8; ++q) {
            sum += sSup[tid + 32 * q];
            mx = fmaxf(mx, sSup[256 + tid + 32 * q]);
        }
        feats[(size_t)g * 128 + foff + tid] = sum * (1.0f / NP);
        feats[(size_t)g * 128 + foff + 32 + tid] = mx;
    }
}

__global__ __launch_bounds__(256, 3) void graph_fused(
        const float* __restrict__ S1, const int* __restrict__ cols1,
        const float* __restrict__ vals1, const float* __restrict__ b1a,
        const float* __restrict__ W1b, const float* __restrict__ b1b,
        const float* __restrict__ S2, const int* __restrict__ cols2,
        const float* __restrict__ vals2, const float* __restrict__ b2a,
        const float* __restrict__ W2b, const float* __restrict__ b2b,
        float* __restrict__ feats) {
    __shared__ float sSup[N2P * 33];       // 26.4 KB
    const int bid = blockIdx.x;
    const int g = bid >> 1;                // interleave branches: tail balance
    if ((bid & 1) == 0)
        graph_phase<N1P>(g, S1, cols1, vals1, b1a, W1b, b1b, feats, 0, sSup);
    else
        graph_phase<N2P>(g, S2, cols2, vals2, b2a, W2b, b2b, feats, 64, sSup);
}

// ---------------------------------------------------------------------------
// Fallback: proven R5 monolithic per-graph kernel (used if ws too small)
// ---------------------------------------------------------------------------
template <int ST>
__device__ __forceinline__ void agg_phase_fb(int base, int NPv,
                                             const int* __restrict__ cols,
                                             const float* __restrict__ vals,
                                             const float* __restrict__ sup,
                                             float bias, float* __restrict__ outh,
                                             int tid) {
    const int h = tid & 31;
    for (int n = tid >> 5; n < NPv; n += 8) {
        const int4* c4 = (const int4*)(cols + ((size_t)base + n) * 16);
        const float4* v4 = (const float4*)(vals + ((size_t)base + n) * 16);
        float a = bias;
#pragma unroll
        for (int q = 0; q < 4; ++q) {
            const int4 c = c4[q];
            const float4 v = v4[q];
            a += v.x * sup[(c.x - base) * ST + h];
            a += v.y * sup[(c.y - base) * ST + h];
            a += v.z * sup[(c.z - base) * ST + h];
            a += v.w * sup[(c.w - base) * ST + h];
        }
        outh[n * ST + h] = fmaxf(a, 0.f);
    }
}

template <int NP>
__device__ void branch_graph(int g,
                             const float* __restrict__ X,
                             const int* __restrict__ cols,
                             const float* __restrict__ vals,
                             const float* __restrict__ Wa,
                             const float* __restrict__ ba,
                             const float* __restrict__ Wb,
                             const float* __restrict__ bb,
                             float* __restrict__ feats, int foff,
                             float* sSup, float* sH) {
    constexpr int ST = 33;
    constexpr int KC = 16;
    constexpr int SXS = 20;
    constexpr int NSLOT = NP * 4;
    constexpr int PSL = (NSLOT + 255) / 256;

    const int tid = threadIdx.x;
    const int base = g * NP;
    const float* xg = X + (size_t)base * NP;
    const float bA = ba[tid & 31];
    const float bB = bb[tid & 31];

    float* sX = sSup;

    float acc[32];
#pragma unroll
    for (int c = 0; c < 32; ++c) acc[c] = 0.f;

    const int NC = (NP + KC - 1) / KC;

    float4 cur[PSL], nxt[PSL];

    auto load_chunk = [&](int kc, float4* buf) {
        const int k0 = kc * KC;
        const int kw = (NP - k0) < KC ? (NP - k0) : KC;
        const int pieces = kw >> 2;
#pragma unroll
        for (int q = 0; q < PSL; ++q) {
            const int i = tid + q * 256;
            float4 v = make_float4(0.f, 0.f, 0.f, 0.f);
            if (i < NSLOT) {
                const int row = i >> 2, p = i & 3;
                if (p < pieces)
                    v = *(const float4*)(xg + (size_t)row * NP + k0 + p * 4);
            }
            buf[q] = v;
        }
    };
    auto store_chunk = [&](const float4* buf) {
#pragma unroll
        for (int q = 0; q < PSL; ++q) {
            const int i = tid + q * 256;
            if (i < NSLOT) {
                const int row = i >> 2, p = i & 3;
                *(float4*)&sX[row * SXS + p * 4] = buf[q];
            }
        }
    };

    load_chunk(0, cur);
#pragma unroll 1
    for (int kc = 0; kc < NC; ++kc) {
        __syncthreads();
        store_chunk(cur);
        __syncthreads();
        if (kc + 1 < NC) load_chunk(kc + 1, nxt);
        const int k0 = kc * KC;
        const int kw = (NP - k0) < KC ? (NP - k0) : KC;
        if (tid < NP) {
            const float* xrow = &sX[tid * SXS];
            const float* wb0 = Wa + (size_t)k0 * 32;
#pragma unroll 1
            for (int k4 = 0; k4 < kw; k4 += 4) {
                const float4 x4 = *(const float4*)&xrow[k4];
#pragma unroll
                for (int kk = 0; kk < 4; ++kk) {
                    const float xs = (&x4.x)[kk];
                    const float* w = wb0 + (k4 + kk) * 32;
#pragma unroll
                    for (int c4 = 0; c4 < 8; ++c4) {
                        const float4 wv = *(const float4*)&w[c4 * 4];
                        acc[c4 * 4 + 0] += xs * wv.x;
                        acc[c4 * 4 + 1] += xs * wv.y;
                        acc[c4 * 4 + 2] += xs * wv.z;
                        acc[c4 * 4 + 3] += xs * wv.w;
                    }
                }
            }
        }
#pragma unroll
        for (int q = 0; q < PSL; ++q) cur[q] = nxt[q];
    }
    __syncthreads();

    if (tid < NP) {
#pragma unroll
        for (int c4 = 0; c4 < 8; ++c4) {
            float4 o;
            o.x = acc[c4 * 4 + 0]; o.y = acc[c4 * 4 + 1];
            o.z = acc[c4 * 4 + 2]; o.w = acc[c4 * 4 + 3];
            *(float4*)&sSup[tid * ST + c4 * 4] = o;
        }
    }
    __syncthreads();

    agg_phase_fb<ST>(base, NP, cols, vals, sSup, bA, sH, tid);
    __syncthreads();

    if (tid < NP) {
        float acc2[32];
#pragma unroll
        for (int c = 0; c < 32; ++c) acc2[c] = 0.f;
        const float* xrow = &sH[tid * ST];
#pragma unroll 1
        for (int k4 = 0; k4 < 32; k4 += 4) {
            const float4 x4 = *(const float4*)&xrow[k4];
#pragma unroll
            for (int kk = 0; kk < 4; ++kk) {
                const float xs = (&x4.x)[kk];
                const float* w = Wb + (k4 + kk) * 32;
#pragma unroll
                for (int c4 = 0; c4 < 8; ++c4) {
                    const float4 wv = *(const float4*)&w[c4 * 4];
                    acc2[c4 * 4 + 0] += xs * wv.x;
                    acc2[c4 * 4 + 1] += xs * wv.y;
                    acc2[c4 * 4 + 2] += xs * wv.z;
                    acc2[c4 * 4 + 3] += xs * wv.w;
                }
            }
        }
#pragma unroll
        for (int c4 = 0; c4 < 8; ++c4) {
            float4 o;
            o.x = acc2[c4 * 4 + 0]; o.y = acc2[c4 * 4 + 1];
            o.z = acc2[c4 * 4 + 2]; o.w = acc2[c4 * 4 + 3];
            *(float4*)&sSup[tid * ST + c4 * 4] = o;
        }
    }
    __syncthreads();

    agg_phase_fb<ST>(base, NP, cols, vals, sSup, bB, sH, tid);
    __syncthreads();

    const int h = tid & 31, sl = tid >> 5;
    float sum = 0.f, mx = -1e30f;
    for (int n = sl; n < NP; n += 8) {
        const float v = sH[n * ST + h];
        sum += v;
        mx = fmaxf(mx, v);
    }
    float* sS = sSup;
    float* sM = sSup + 256;
    sS[tid] = sum;
    sM[tid] = mx;
    __syncthreads();
    if (tid < 32) {
#pragma unroll
        for (int q = 1; q < 8; ++q) {
            sum += sS[tid + 32 * q];
            mx = fmaxf(mx, sM[tid + 32 * q]);
        }
        feats[(size_t)g * 128 + foff + tid] = sum * (1.0f / NP);
        feats[(size_t)g * 128 + foff + 32 + tid] = mx;
    }
}

__global__ __launch_bounds__(256, 3) void fused_branches(
        const float* __restrict__ x1, const int* __restrict__ cols1,
        const float* __restrict__ vals1,
        const float* __restrict__ W1a, const float* __restrict__ b1a,
        const float* __restrict__ W1b, const float* __restrict__ b1b,
        const float* __restrict__ x2, const int* __restrict__ cols2,
        const float* __restrict__ vals2,
        const float* __restrict__ W2a, const float* __restrict__ b2a,
        const float* __restrict__ W2b, const float* __restrict__ b2b,
        float* __restrict__ feats) {
    __shared__ float sSup[N2P * 33];
    __shared__ float sH[N2P * 33];
    const int bid = blockIdx.x;
    if (bid < NB) {
        branch_graph<N1P>(bid, x1, cols1, vals1, W1a, b1a, W1b, b1b, feats, 0,
                          sSup, sH);
    } else {
        branch_graph<N2P>(bid - NB, x2, cols2, vals2, W2a, b2a, W2b, b2b, feats,
                          64, sSup, sH);
    }
}

// ---------------------------------------------------------------------------
// MLP head: [B,128] -> relu(fc1) -> relu(fc2) -> fc3 -> [B,2]
// ---------------------------------------------------------------------------
__global__ __launch_bounds__(256) void mlp_head(const float* __restrict__ feats,
                                                const float* __restrict__ W1,
                                                const float* __restrict__ b1,
                                                const float* __restrict__ W2,
                                                const float* __restrict__ b2,
                                                const float* __restrict__ W3,
                                                const float* __restrict__ b3,
                                                float* __restrict__ out) {
    __shared__ float sW1[128 * 32];
    __shared__ float sW2[32 * 16];
    __shared__ float sW3[16 * 2];
    __shared__ float sB1[32], sB2[16], sB3[2];
    __shared__ float sF[8 * 128];
    __shared__ float sH1[8 * 32];
    __shared__ float sH2[8 * 16];

    const int tid = threadIdx.x;
    for (int idx = tid; idx < 128 * 32; idx += 256) sW1[idx] = W1[idx];
    for (int idx = tid; idx < 32 * 16; idx += 256) sW2[idx] = W2[idx];
    if (tid < 32) { sW3[tid] = W3[tid]; sB1[tid] = b1[tid]; }
    if (tid < 16) sB2[tid] = b2[tid];
    if (tid < 2) sB3[tid] = b3[tid];
    const long g0 = (long)blockIdx.x * 8;
    for (int idx = tid; idx < 1024; idx += 256) sF[idx] = feats[g0 * 128 + idx];
    __syncthreads();

    const int g = tid >> 5, h = tid & 31;
    float a1 = sB1[h];
#pragma unroll 4
    for (int k = 0; k < 128; ++k) a1 += sF[g * 128 + k] * sW1[k * 32 + h];
    sH1[g * 32 + h] = fmaxf(a1, 0.f);
    __syncthreads();

    if (h < 16) {
        float a2 = sB2[h];
#pragma unroll
        for (int k = 0; k < 32; ++k) a2 += sH1[g * 32 + k] * sW2[k * 16 + h];
        sH2[g * 16 + h] = fmaxf(a2, 0.f);
    }
    __syncthreads();

    if (h < 2) {
        float a3 = sB3[h];
#pragma unroll
        for (int k = 0; k < 16; ++k) a3 += sH2[g * 16 + k] * sW3[k * 2 + h];
        out[(g0 + g) * 2 + h] = a3;
    }
}

// ---------------------------------------------------------------------------
extern "C" void kernel_launch(void* const* d_in, const int* in_sizes, int n_in,
                              void* d_out, int out_size, void* d_ws, size_t ws_size,
                              hipStream_t stream) {
    const int*   cols1 = (const int*)d_in[1];
    const float* vals1 = (const float*)d_in[2];
    const float* x1    = (const float*)d_in[3];
    const int*   cols2 = (const int*)d_in[5];
    const float* vals2 = (const float*)d_in[6];
    const float* x2    = (const float*)d_in[7];
    const float* W1a = (const float*)d_in[8];
    const float* b1a = (const float*)d_in[9];
    const float* W1b = (const float*)d_in[10];
    const float* b1b = (const float*)d_in[11];
    const float* W2a = (const float*)d_in[12];
    const float* b2a = (const float*)d_in[13];
    const float* W2b = (const float*)d_in[14];
    const float* b2b = (const float*)d_in[15];
    const float* fc1_W = (const float*)d_in[16];
    const float* fc1_b = (const float*)d_in[17];
    const float* fc2_W = (const float*)d_in[18];
    const float* fc2_b = (const float*)d_in[19];
    const float* fc3_W = (const float*)d_in[20];
    const float* fc3_b = (const float*)d_in[21];
    float* out = (float*)d_out;

    float* feats = (float*)d_ws;                       // NB*128 floats
    const size_t FEATS_N = (size_t)NB * 128;
    const size_t S1_N = (size_t)NB * N1P * 32;         // 3.80M floats
    const size_t S2_N = (size_t)NB * N2P * 32;         // 6.55M floats
    const size_t need = (FEATS_N + S1_N + S2_N) * sizeof(float);  // ~42 MB

    if (ws_size >= need) {
        float* S1 = feats + FEATS_N;
        float* S2 = S1 + S1_N;
        gemm1_kernel<<<T1 + T2, 256, 0, stream>>>(x1, W1a, S1, x2, W2a, S2);
        graph_fused<<<2 * NB, 256, 0, stream>>>(
            S1, cols1, vals1, b1a, W1b, b1b,
            S2, cols2, vals2, b2a, W2b, b2b, feats);
    } else {
        fused_branches<<<2 * NB, 256, 0, stream>>>(
            x1, cols1, vals1, W1a, b1a, W1b, b1b,
            x2, cols2, vals2, W2a, b2a, W2b, b2b, feats);
    }

    mlp_head<<<NB / 8, 256, 0, stream>>>(feats, fc1_W, fc1_b, fc2_W, fc2_b,
                                         fc3_W, fc3_b, out);
}